// Round 2
// baseline (633.563 us; speedup 1.0000x reference)
//
#include <hip/hip_runtime.h>
#include <math.h>

typedef __bf16 bf16;
typedef bf16 bf16x4 __attribute__((ext_vector_type(4)));
typedef bf16 bf16x8 __attribute__((ext_vector_type(8)));
typedef float f32x4 __attribute__((ext_vector_type(4)));

#define BATCH 65536
#define QD 32
#define HD 512
#define NT 528
#define BM 64
#define BIAS_C 2.0f

// ws layout (bf16), all weights transposed to [out_feat][k]:
#define OFF_WIN  0         // Wt_in  [512][32]
#define OFF_WH1  16384     // Wt_h1  [512][512]
#define OFF_WH2  278528    // Wt_h2  [512][512]
#define OFF_WOUT 540672    // Wt_out [512][512]
#define OFF_WO   802816    // Wt_o   [528][512]
#define WT_TOTAL 1073152

#define MFMA(a, b, c) __builtin_amdgcn_mfma_f32_16x16x32_bf16((a), (b), (c), 0, 0, 0)

// Coalesced-read transpose: thread reads W[k][n] at flat idx (coalesced),
// writes wt[n*K + k] (scattered 2B, absorbed by L2 — wt stays L2/L3 resident).
__global__ __launch_bounds__(256) void prep_weights(
    const float* __restrict__ W_in, const float* __restrict__ W_h1,
    const float* __restrict__ W_h2, const float* __restrict__ W_out,
    const float* __restrict__ W_o, bf16* __restrict__ wt)
{
    int idx = blockIdx.x * 256 + threadIdx.x;
    if (idx >= WT_TOTAL) return;
    if (idx < 16384) {
        int k = idx >> 9, n = idx & 511;
        wt[OFF_WIN + n * QD + k] = (bf16)W_in[idx];
    } else if (idx < 16384 + 262144) {
        int t = idx - 16384; int k = t >> 9, n = t & 511;
        wt[OFF_WH1 + n * HD + k] = (bf16)W_h1[t];
    } else if (idx < 16384 + 2 * 262144) {
        int t = idx - (16384 + 262144); int k = t >> 9, n = t & 511;
        wt[OFF_WH2 + n * HD + k] = (bf16)W_h2[t];
    } else if (idx < 16384 + 3 * 262144) {
        int t = idx - (16384 + 2 * 262144); int k = t >> 9, n = t & 511;
        wt[OFF_WOUT + n * HD + k] = (bf16)W_out[t];
    } else {
        int t = idx - (16384 + 3 * 262144); int k = t / NT, n = t - k * NT;
        wt[OFF_WO + n * HD + k] = (bf16)W_o[t];
    }
}

// x LDS layout: x[m][f], m=batch(0..63), f=feat(0..511), bf16.
// 16B chunks XOR-swizzled: byte_off(m, f) = m*1024 + (((f>>3) ^ m) << 4) + ((f&7)<<1)
__device__ __forceinline__ int xbyte(int m, int f) {
    return m * 1024 + ((((f >> 3)) ^ m) << 4) + ((f & 7) << 1);
}

// L storage (phase 2): per item il (0..15), hi at il*2048, lo at 32768 + il*2048.
__device__ __forceinline__ int lbyte(int il, int r, int c) {
    return il * 2048 + r * 64 + ((((c >> 3)) ^ (r & 3) ^ (il & 3)) << 4) + ((c & 7) << 1);
}

__device__ __forceinline__ void writeL(unsigned char* smem, int il, int p, float v) {
    int r_, c_;
    if (p < QD) {
        r_ = p; c_ = p; v += BIAS_C;
    } else {
        int t = p - QD;
        r_ = (int)((1.0f + sqrtf(8.0f * (float)t + 1.0f)) * 0.5f);
        while (r_ * (r_ - 1) / 2 > t) --r_;
        while ((r_ + 1) * r_ / 2 <= t) ++r_;
        c_ = t - r_ * (r_ - 1) / 2;
    }
    bf16 hi = (bf16)v;
    bf16 lo = (bf16)(v - (float)hi);
    int off = lbyte(il, r_, c_);
    *(bf16*)(smem + off) = hi;
    *(bf16*)(smem + 32768 + off) = lo;
}

// 512 threads = 8 waves; each wave owns a 64-feature slice (4 x 16-feat tiles).
// LDS 64KB -> 2 blocks/CU -> 16 waves/CU (4/SIMD) vs 8 waves/CU before.
__global__ __launch_bounds__(512, 4) void fused_kernel(
    const float* __restrict__ q,
    const float* __restrict__ b_in, const float* __restrict__ b_h1,
    const float* __restrict__ b_h2, const float* __restrict__ b_out,
    const float* __restrict__ b_o,
    const bf16* __restrict__ wt, float* __restrict__ out)
{
    __shared__ __attribute__((aligned(16))) unsigned char smem[65536];
    const int tid  = threadIdx.x;
    const int lane = tid & 63;
    const int wave = tid >> 6;     // 0..7
    const int l15  = lane & 15;
    const int quad = lane >> 4;
    const int blk  = blockIdx.x;

    const f32x4 zf = {0.f, 0.f, 0.f, 0.f};
    f32x4 acc[4][4];               // [feat tile rt][batch tile ct]

    // ===================== GEMM0: x0 = relu(q @ W_in + b_in) =====================
    {
        bf16x8 bfr[4];
        #pragma unroll
        for (int ct = 0; ct < 4; ++ct) {
            const float* qp = q + (size_t)(blk * 64 + ct * 16 + l15) * QD + quad * 8;
            f32x4 lo = *(const f32x4*)qp;
            f32x4 hi = *(const f32x4*)(qp + 4);
            bf16x8 b;
            #pragma unroll
            for (int j = 0; j < 4; ++j) { b[j] = (bf16)lo[j]; b[4 + j] = (bf16)hi[j]; }
            bfr[ct] = b;
        }
        #pragma unroll
        for (int rt = 0; rt < 4; ++rt) {
            int feat = wave * 64 + rt * 16 + l15;
            bf16x8 a = *(const bf16x8*)(wt + OFF_WIN + feat * QD + quad * 8);
            #pragma unroll
            for (int ct = 0; ct < 4; ++ct)
                acc[rt][ct] = MFMA(a, bfr[ct], zf);
        }
        #pragma unroll
        for (int rt = 0; rt < 4; ++rt) {
            int f0 = wave * 64 + rt * 16 + quad * 4;
            f32x4 bias = *(const f32x4*)(b_in + f0);
            #pragma unroll
            for (int ct = 0; ct < 4; ++ct) {
                int m = ct * 16 + l15;
                bf16x4 w;
                #pragma unroll
                for (int r = 0; r < 4; ++r) {
                    float v = acc[rt][ct][r] + bias[r];
                    v = v > 0.f ? v : 0.f;
                    w[r] = (bf16)v;
                }
                *(bf16x4*)(smem + xbyte(m, f0)) = w;
            }
        }
    }
    __syncthreads();

    // ===================== Hidden layers h1, h2 (residual) and W_out =====================
    const bf16*  WL[3] = { wt + OFF_WH1, wt + OFF_WH2, wt + OFF_WOUT };
    const float* BL[3] = { b_h1, b_h2, b_out };
    #pragma unroll
    for (int L = 0; L < 3; ++L) {
        #pragma unroll
        for (int rt = 0; rt < 4; ++rt)
            #pragma unroll
            for (int ct = 0; ct < 4; ++ct)
                acc[rt][ct] = zf;
        const bf16* W = WL[L];
        #pragma unroll 4
        for (int kk = 0; kk < 16; ++kk) {
            bf16x8 bfr2[4];
            #pragma unroll
            for (int ct = 0; ct < 4; ++ct) {
                int m = ct * 16 + l15;
                bfr2[ct] = *(const bf16x8*)(smem + m * 1024 + (((kk * 4 + quad) ^ m) << 4));
            }
            #pragma unroll
            for (int rt = 0; rt < 4; ++rt) {
                int feat = wave * 64 + rt * 16 + l15;
                bf16x8 a = *(const bf16x8*)(W + feat * HD + kk * 32 + quad * 8);
                #pragma unroll
                for (int ct = 0; ct < 4; ++ct)
                    acc[rt][ct] = MFMA(a, bfr2[ct], acc[rt][ct]);
            }
        }
        __syncthreads();   // all waves done reading x before overwrite
        {
            const float* Bv = BL[L];
            #pragma unroll
            for (int rt = 0; rt < 4; ++rt) {
                int f0 = wave * 64 + rt * 16 + quad * 4;
                f32x4 bias = *(const f32x4*)(Bv + f0);
                #pragma unroll
                for (int ct = 0; ct < 4; ++ct) {
                    int m = ct * 16 + l15;
                    unsigned char* p = smem + xbyte(m, f0);
                    bf16x4 w;
                    if (L < 2) {   // relu + residual
                        bf16x4 old = *(const bf16x4*)p;
                        #pragma unroll
                        for (int r = 0; r < 4; ++r) {
                            float v = acc[rt][ct][r] + bias[r];
                            v = v > 0.f ? v : 0.f;
                            v += (float)old[r];
                            w[r] = (bf16)v;
                        }
                    } else {       // embed: no relu, no residual
                        #pragma unroll
                        for (int r = 0; r < 4; ++r) {
                            float v = acc[rt][ct][r] + bias[r];
                            w[r] = (bf16)v;
                        }
                    }
                    *(bf16x4*)p = w;
                }
            }
        }
        __syncthreads();
    }

    // ===================== L4: L_params^T = W_o^T @ embed^T  (528 feats) =====================
    f32x4 acc_ex = zf;
    #pragma unroll
    for (int rt = 0; rt < 4; ++rt)
        #pragma unroll
        for (int ct = 0; ct < 4; ++ct)
            acc[rt][ct] = zf;
    #pragma unroll 4
    for (int kk = 0; kk < 16; ++kk) {
        bf16x8 bfr2[4];
        #pragma unroll
        for (int ct = 0; ct < 4; ++ct) {
            int m = ct * 16 + l15;
            bfr2[ct] = *(const bf16x8*)(smem + m * 1024 + (((kk * 4 + quad) ^ m) << 4));
        }
        #pragma unroll
        for (int rt = 0; rt < 4; ++rt) {
            int feat = wave * 64 + rt * 16 + l15;
            bf16x8 a = *(const bf16x8*)(wt + OFF_WO + feat * HD + kk * 32 + quad * 8);
            #pragma unroll
            for (int ct = 0; ct < 4; ++ct)
                acc[rt][ct] = MFMA(a, bfr2[ct], acc[rt][ct]);
        }
        // extra feature tile 512..527: wave w (w<4) covers batch group ct == w
        if (wave < 4) {
            bf16x8 aex = *(const bf16x8*)(wt + OFF_WO + (512 + l15) * HD + kk * 32 + quad * 8);
            if (wave == 0) acc_ex = MFMA(aex, bfr2[0], acc_ex);
            else if (wave == 1) acc_ex = MFMA(aex, bfr2[1], acc_ex);
            else if (wave == 2) acc_ex = MFMA(aex, bfr2[2], acc_ex);
            else acc_ex = MFMA(aex, bfr2[3], acc_ex);
        }
    }
    __syncthreads();   // x (embed) dead; reuse smem for L tiles

    // hoist b_o bias loads
    f32x4 bo4[4];
    #pragma unroll
    for (int rt = 0; rt < 4; ++rt)
        bo4[rt] = *(const f32x4*)(b_o + wave * 64 + rt * 16 + quad * 4);
    f32x4 bo_ex = zf;
    if (wave < 4) bo_ex = *(const f32x4*)(b_o + 512 + quad * 4);

    // ===================== Phase 2: build L (hi/lo bf16) and M = L L^T =====================
    {
        unsigned long long* z = (unsigned long long*)smem;
        #pragma unroll
        for (int i = 0; i < 16; ++i) z[tid + 512 * i] = 0ull;
    }
    __syncthreads();

    #pragma unroll
    for (int g = 0; g < 4; ++g) {
        // ---- write L values for items = batch cols g*16 .. g*16+15 (il = l15) ----
        const int il = l15;
        #pragma unroll
        for (int rt = 0; rt < 4; ++rt) {
            #pragma unroll
            for (int r = 0; r < 4; ++r) {
                int p = wave * 64 + rt * 16 + quad * 4 + r;
                writeL(smem, il, p, acc[rt][g][r] + bo4[rt][r]);
            }
        }
        if (wave == g) {
            #pragma unroll
            for (int r = 0; r < 4; ++r)
                writeL(smem, il, 512 + quad * 4 + r, acc_ex[r] + bo_ex[r]);
        }
        __syncthreads();
        // ---- per-item M = L L^T via hi/lo-split MFMA; wave handles items wave*2..+1 ----
        #pragma unroll
        for (int c = 0; c < 2; ++c) {
            int it = wave * 2 + c;
            bf16x8 Fh[2], Fl[2];
            #pragma unroll
            for (int tl = 0; tl < 2; ++tl) {
                int m = tl * 16 + l15;
                int ch = quad ^ (m & 3) ^ (it & 3);
                int off = it * 2048 + m * 64 + (ch << 4);
                Fh[tl] = *(const bf16x8*)(smem + off);
                Fl[tl] = *(const bf16x8*)(smem + 32768 + off);
            }
            long base = ((long)(blk * 64 + g * 16 + it)) * 1024;
            #pragma unroll
            for (int mt = 0; mt < 2; ++mt) {
                #pragma unroll
                for (int nt = 0; nt < 2; ++nt) {
                    f32x4 mm = MFMA(Fh[mt], Fh[nt], zf);
                    mm = MFMA(Fh[mt], Fl[nt], mm);
                    mm = MFMA(Fl[mt], Fh[nt], mm);
                    #pragma unroll
                    for (int r = 0; r < 4; ++r)
                        out[base + (long)(mt * 16 + quad * 4 + r) * 32 + nt * 16 + l15] = mm[r];
                }
            }
        }
        __syncthreads();   // L region reused by next group
    }
}

extern "C" void kernel_launch(void* const* d_in, const int* in_sizes, int n_in,
                              void* d_out, int out_size, void* d_ws, size_t ws_size,
                              hipStream_t stream)
{
    const float* q     = (const float*)d_in[0];
    const float* b_in  = (const float*)d_in[2];
    const float* b_h1  = (const float*)d_in[4];
    const float* b_h2  = (const float*)d_in[6];
    const float* b_out = (const float*)d_in[8];
    const float* b_o   = (const float*)d_in[10];
    const float* W_in  = (const float*)d_in[1];
    const float* W_h1  = (const float*)d_in[3];
    const float* W_h2  = (const float*)d_in[5];
    const float* W_out = (const float*)d_in[7];
    const float* W_o   = (const float*)d_in[9];
    float* out = (float*)d_out;
    bf16* wt = (bf16*)d_ws;

    prep_weights<<<(WT_TOTAL + 255) / 256, 256, 0, stream>>>(W_in, W_h1, W_h2, W_out, W_o, wt);
    fused_kernel<<<BATCH / BM, 512, 0, stream>>>(q, b_in, b_h1, b_h2, b_out, b_o, wt, out);
}

// Round 3
// 495.210 us; speedup vs baseline: 1.2794x; 1.2794x over previous
//
#include <hip/hip_runtime.h>
#include <math.h>

typedef __bf16 bf16;
typedef bf16 bf16x4 __attribute__((ext_vector_type(4)));
typedef bf16 bf16x8 __attribute__((ext_vector_type(8)));
typedef float f32x4 __attribute__((ext_vector_type(4)));

#define BATCH 65536
#define QD 32
#define HD 512
#define NT 528
#define BM 64
#define BIAS_C 2.0f

// ws layout (bf16): weights packed as [nt][kt] tiles of 16 feats x 32 k = 512 elems (1 KB).
// element (f = nt*16+fi, k = kt*32+ki) at base + (nt*KT + ... ) -- we use tile index = nt*(K/32)+kt
// A-frag load for a wave: base + tile*512 + l15*32 + quad*8  -> one coalesced 1 KB load.
#define OFF_WIN  0         // W_in^T tiled: 32 nt x 1 kt
#define OFF_WH1  16384
#define OFF_WH2  278528
#define OFF_WOUT 540672
#define OFF_WO   802816    // 33 nt x 16 kt
#define WT_TOTAL 1073152

#define MFMA(a, b, c) __builtin_amdgcn_mfma_f32_16x16x32_bf16((a), (b), (c), 0, 0, 0)

// Coalesced bf16 writes (consecutive idx -> consecutive output), scattered cached fp32 reads.
__global__ __launch_bounds__(256) void prep_weights(
    const float* __restrict__ W_in, const float* __restrict__ W_h1,
    const float* __restrict__ W_h2, const float* __restrict__ W_out,
    const float* __restrict__ W_o, bf16* __restrict__ wt)
{
    int idx = blockIdx.x * 256 + threadIdx.x;
    if (idx >= WT_TOTAL) return;
    float v;
    if (idx < OFF_WH1) {
        int nt = idx >> 9, r = idx & 511, fi = r >> 5, ki = r & 31;
        v = W_in[ki * HD + nt * 16 + fi];
    } else if (idx < OFF_WH2) {
        int t = idx - OFF_WH1, tile = t >> 9, r = t & 511;
        int nt = tile >> 4, kt = tile & 15, fi = r >> 5, ki = r & 31;
        v = W_h1[(kt * 32 + ki) * HD + nt * 16 + fi];
    } else if (idx < OFF_WOUT) {
        int t = idx - OFF_WH2, tile = t >> 9, r = t & 511;
        int nt = tile >> 4, kt = tile & 15, fi = r >> 5, ki = r & 31;
        v = W_h2[(kt * 32 + ki) * HD + nt * 16 + fi];
    } else if (idx < OFF_WO) {
        int t = idx - OFF_WOUT, tile = t >> 9, r = t & 511;
        int nt = tile >> 4, kt = tile & 15, fi = r >> 5, ki = r & 31;
        v = W_out[(kt * 32 + ki) * HD + nt * 16 + fi];
    } else {
        int t = idx - OFF_WO, tile = t >> 9, r = t & 511;
        int nt = tile >> 4, kt = tile & 15, fi = r >> 5, ki = r & 31;
        v = W_o[(kt * 32 + ki) * NT + nt * 16 + fi];
    }
    wt[idx] = (bf16)v;
}

// x LDS layout: x[m][f], m=batch(0..63), f=feat(0..511), bf16, XOR-swizzled 16B chunks.
__device__ __forceinline__ int xbyte(int m, int f) {
    return m * 1024 + ((((f >> 3)) ^ m) << 4) + ((f & 7) << 1);
}

// L storage (phase 2): per item il (0..15), hi at il*2048, lo at 32768 + il*2048.
__device__ __forceinline__ int lbyte(int il, int r, int c) {
    return il * 2048 + r * 64 + ((((c >> 3)) ^ (r & 3) ^ (il & 3)) << 4) + ((c & 7) << 1);
}

__device__ __forceinline__ void writeL(unsigned char* smem, int il, int p, float v) {
    int r_, c_;
    if (p < QD) {
        r_ = p; c_ = p; v += BIAS_C;
    } else {
        int t = p - QD;
        r_ = (int)((1.0f + sqrtf(8.0f * (float)t + 1.0f)) * 0.5f);
        while (r_ * (r_ - 1) / 2 > t) --r_;
        while ((r_ + 1) * r_ / 2 <= t) ++r_;
        c_ = t - r_ * (r_ - 1) / 2;
    }
    bf16 hi = (bf16)v;
    bf16 lo = (bf16)(v - (float)hi);
    int off = lbyte(il, r_, c_);
    *(bf16*)(smem + off) = hi;
    *(bf16*)(smem + 32768 + off) = lo;
}

// 1024 threads = 16 waves; each wave owns a 32-feature slice (2 x 16-feat tiles).
// acc = 32 f32/thread -> fits 128-reg cap at 4 waves/SIMD with NO spills.
// 1 block/CU (LDS 64KB + 16 waves), grid 1024 -> 4 sequential blocks/CU.
__global__ __launch_bounds__(1024, 4) void fused_kernel(
    const float* __restrict__ q,
    const float* __restrict__ b_in, const float* __restrict__ b_h1,
    const float* __restrict__ b_h2, const float* __restrict__ b_out,
    const float* __restrict__ b_o,
    const bf16* __restrict__ wt, float* __restrict__ out)
{
    __shared__ __attribute__((aligned(16))) unsigned char smem[65536];
    const int tid  = threadIdx.x;
    const int lane = tid & 63;
    const int wave = tid >> 6;     // 0..15
    const int l15  = lane & 15;
    const int quad = lane >> 4;
    const int blk  = blockIdx.x;

    const f32x4 zf = {0.f, 0.f, 0.f, 0.f};
    f32x4 acc[2][4];               // [feat tile rt][batch tile ct]

    // ===================== GEMM0: x0 = relu(q @ W_in + b_in) =====================
    {
        bf16x8 bfr[4];
        #pragma unroll
        for (int ct = 0; ct < 4; ++ct) {
            const float* qp = q + (size_t)(blk * 64 + ct * 16 + l15) * QD + quad * 8;
            f32x4 lo = *(const f32x4*)qp;
            f32x4 hi = *(const f32x4*)(qp + 4);
            bf16x8 b;
            #pragma unroll
            for (int j = 0; j < 4; ++j) { b[j] = (bf16)lo[j]; b[4 + j] = (bf16)hi[j]; }
            bfr[ct] = b;
        }
        #pragma unroll
        for (int rt = 0; rt < 2; ++rt) {
            bf16x8 a = *(const bf16x8*)(wt + OFF_WIN + (wave * 2 + rt) * 512 + l15 * 32 + quad * 8);
            #pragma unroll
            for (int ct = 0; ct < 4; ++ct)
                acc[rt][ct] = MFMA(a, bfr[ct], zf);
        }
        #pragma unroll
        for (int rt = 0; rt < 2; ++rt) {
            int f0 = wave * 32 + rt * 16 + quad * 4;
            f32x4 bias = *(const f32x4*)(b_in + f0);
            #pragma unroll
            for (int ct = 0; ct < 4; ++ct) {
                int m = ct * 16 + l15;
                bf16x4 w;
                #pragma unroll
                for (int r = 0; r < 4; ++r) {
                    float v = acc[rt][ct][r] + bias[r];
                    v = v > 0.f ? v : 0.f;
                    w[r] = (bf16)v;
                }
                *(bf16x4*)(smem + xbyte(m, f0)) = w;
            }
        }
    }
    __syncthreads();

    // ===================== Hidden layers h1, h2 (residual) and W_out =====================
    const bf16*  WL[3] = { wt + OFF_WH1, wt + OFF_WH2, wt + OFF_WOUT };
    const float* BL[3] = { b_h1, b_h2, b_out };
    #pragma unroll
    for (int L = 0; L < 3; ++L) {
        #pragma unroll
        for (int rt = 0; rt < 2; ++rt)
            #pragma unroll
            for (int ct = 0; ct < 4; ++ct)
                acc[rt][ct] = zf;
        const bf16* W = WL[L];
        #pragma unroll 2
        for (int kk = 0; kk < 16; ++kk) {
            bf16x8 bfr2[4];
            #pragma unroll
            for (int ct = 0; ct < 4; ++ct) {
                int m = ct * 16 + l15;
                bfr2[ct] = *(const bf16x8*)(smem + m * 1024 + (((kk * 4 + quad) ^ m) << 4));
            }
            #pragma unroll
            for (int rt = 0; rt < 2; ++rt) {
                // tile index = nt*16 + kt, nt = wave*2+rt, kt = kk -> coalesced 1KB wave load
                bf16x8 a = *(const bf16x8*)(W + ((wave * 2 + rt) * 16 + kk) * 512 + l15 * 32 + quad * 8);
                #pragma unroll
                for (int ct = 0; ct < 4; ++ct)
                    acc[rt][ct] = MFMA(a, bfr2[ct], acc[rt][ct]);
            }
        }
        __syncthreads();   // all waves done reading x before overwrite
        {
            const float* Bv = BL[L];
            #pragma unroll
            for (int rt = 0; rt < 2; ++rt) {
                int f0 = wave * 32 + rt * 16 + quad * 4;
                f32x4 bias = *(const f32x4*)(Bv + f0);
                #pragma unroll
                for (int ct = 0; ct < 4; ++ct) {
                    int m = ct * 16 + l15;
                    unsigned char* p = smem + xbyte(m, f0);
                    bf16x4 w;
                    if (L < 2) {   // relu + residual
                        bf16x4 old = *(const bf16x4*)p;
                        #pragma unroll
                        for (int r = 0; r < 4; ++r) {
                            float v = acc[rt][ct][r] + bias[r];
                            v = v > 0.f ? v : 0.f;
                            v += (float)old[r];
                            w[r] = (bf16)v;
                        }
                    } else {       // embed: no relu, no residual
                        #pragma unroll
                        for (int r = 0; r < 4; ++r) {
                            float v = acc[rt][ct][r] + bias[r];
                            w[r] = (bf16)v;
                        }
                    }
                    *(bf16x4*)p = w;
                }
            }
        }
        __syncthreads();
    }

    // ===================== L4: L_params^T = W_o^T @ embed^T  (528 feats) =====================
    f32x4 acc_ex = zf;
    #pragma unroll
    for (int rt = 0; rt < 2; ++rt)
        #pragma unroll
        for (int ct = 0; ct < 4; ++ct)
            acc[rt][ct] = zf;
    #pragma unroll 2
    for (int kk = 0; kk < 16; ++kk) {
        bf16x8 bfr2[4];
        #pragma unroll
        for (int ct = 0; ct < 4; ++ct) {
            int m = ct * 16 + l15;
            bfr2[ct] = *(const bf16x8*)(smem + m * 1024 + (((kk * 4 + quad) ^ m) << 4));
        }
        #pragma unroll
        for (int rt = 0; rt < 2; ++rt) {
            bf16x8 a = *(const bf16x8*)(wt + OFF_WO + ((wave * 2 + rt) * 16 + kk) * 512 + l15 * 32 + quad * 8);
            #pragma unroll
            for (int ct = 0; ct < 4; ++ct)
                acc[rt][ct] = MFMA(a, bfr2[ct], acc[rt][ct]);
        }
        // extra feature tile 512..527 (nt=32): waves 8..11 cover batch group ct = wave-8
        if (wave >= 8 && wave < 12) {
            bf16x8 aex = *(const bf16x8*)(wt + OFF_WO + (32 * 16 + kk) * 512 + l15 * 32 + quad * 8);
            if (wave == 8) acc_ex = MFMA(aex, bfr2[0], acc_ex);
            else if (wave == 9) acc_ex = MFMA(aex, bfr2[1], acc_ex);
            else if (wave == 10) acc_ex = MFMA(aex, bfr2[2], acc_ex);
            else acc_ex = MFMA(aex, bfr2[3], acc_ex);
        }
    }
    __syncthreads();   // x (embed) dead; reuse smem for L tiles

    // hoist b_o bias loads
    f32x4 bo4[2];
    #pragma unroll
    for (int rt = 0; rt < 2; ++rt)
        bo4[rt] = *(const f32x4*)(b_o + wave * 32 + rt * 16 + quad * 4);
    f32x4 bo_ex = zf;
    if (wave >= 8 && wave < 12) bo_ex = *(const f32x4*)(b_o + 512 + quad * 4);

    // ===================== Phase 2: build L (hi/lo bf16) and M = L L^T =====================
    {
        unsigned long long* z = (unsigned long long*)smem;
        #pragma unroll
        for (int i = 0; i < 8; ++i) z[tid + 1024 * i] = 0ull;
    }
    __syncthreads();

    #pragma unroll
    for (int g = 0; g < 4; ++g) {
        // ---- write L values for items = batch cols g*16 .. g*16+15 (il = l15) ----
        const int il = l15;
        #pragma unroll
        for (int rt = 0; rt < 2; ++rt) {
            #pragma unroll
            for (int r = 0; r < 4; ++r) {
                int p = wave * 32 + rt * 16 + quad * 4 + r;
                writeL(smem, il, p, acc[rt][g][r] + bo4[rt][r]);
            }
        }
        if (wave == 8 + g) {
            #pragma unroll
            for (int r = 0; r < 4; ++r)
                writeL(smem, il, 512 + quad * 4 + r, acc_ex[r] + bo_ex[r]);
        }
        __syncthreads();
        // ---- per-item M = L L^T via hi/lo-split MFMA; wave handles item it == wave ----
        {
            const int it = wave;
            bf16x8 Fh[2], Fl[2];
            #pragma unroll
            for (int tl = 0; tl < 2; ++tl) {
                int m = tl * 16 + l15;
                int ch = quad ^ (m & 3) ^ (it & 3);
                int off = it * 2048 + m * 64 + (ch << 4);
                Fh[tl] = *(const bf16x8*)(smem + off);
                Fl[tl] = *(const bf16x8*)(smem + 32768 + off);
            }
            long base = ((long)(blk * 64 + g * 16 + it)) * 1024;
            #pragma unroll
            for (int mt = 0; mt < 2; ++mt) {
                #pragma unroll
                for (int nt = 0; nt < 2; ++nt) {
                    f32x4 mm = MFMA(Fh[mt], Fh[nt], zf);
                    mm = MFMA(Fh[mt], Fl[nt], mm);
                    mm = MFMA(Fl[mt], Fh[nt], mm);
                    #pragma unroll
                    for (int r = 0; r < 4; ++r)
                        out[base + (long)(mt * 16 + quad * 4 + r) * 32 + nt * 16 + l15] = mm[r];
                }
            }
        }
        __syncthreads();   // L region reused by next group
    }
}

extern "C" void kernel_launch(void* const* d_in, const int* in_sizes, int n_in,
                              void* d_out, int out_size, void* d_ws, size_t ws_size,
                              hipStream_t stream)
{
    const float* q     = (const float*)d_in[0];
    const float* W_in  = (const float*)d_in[1];
    const float* b_in  = (const float*)d_in[2];
    const float* W_h1  = (const float*)d_in[3];
    const float* b_h1  = (const float*)d_in[4];
    const float* W_h2  = (const float*)d_in[5];
    const float* b_h2  = (const float*)d_in[6];
    const float* W_out = (const float*)d_in[7];
    const float* b_out = (const float*)d_in[8];
    const float* W_o   = (const float*)d_in[9];
    const float* b_o   = (const float*)d_in[10];
    float* out = (float*)d_out;
    bf16* wt = (bf16*)d_ws;

    prep_weights<<<(WT_TOTAL + 255) / 256, 256, 0, stream>>>(W_in, W_h1, W_h2, W_out, W_o, wt);
    fused_kernel<<<BATCH / BM, 1024, 0, stream>>>(q, b_in, b_h1, b_h2, b_out, b_o, wt, out);
}